// Round 18
// baseline (143.278 us; speedup 1.0000x reference)
//
#include <hip/hip_runtime.h>
#include <hip/hip_bf16.h>
#include <math.h>

#define B_DIM 8
#define C_DIM 32
#define N_DIM 4096
#define KSL 2048           // k per kh-group
#define NCH (KSL / 64)     // 32 chunks of 64 k

typedef short bf16x8 __attribute__((ext_vector_type(8)));   // 8 bf16 = 4 VGPRs
typedef float f32x4 __attribute__((ext_vector_type(4)));
typedef unsigned int uint4v __attribute__((ext_vector_type(4)));
typedef unsigned short ushort8 __attribute__((ext_vector_type(8)));

__device__ __forceinline__ ushort f2bf_rne(float f) {
  unsigned u = __float_as_uint(f);
  u += 0x7FFF + ((u >> 16) & 1);
  return (ushort)(u >> 16);
}

// Prep A: E[b,n] = exp(mean_c x[b,c,n]).  Hot loop uses the exact identity
// 2*sigmoid(-|ck-cm|) = 2*min(Ek,Em)/(Ek+Em).
__global__ __launch_bounds__(256) void prep_e(const float* __restrict__ x,
                                              float* __restrict__ E) {
  int idx = blockIdx.x * 256 + threadIdx.x;   // 0 .. B*N-1
  int b = idx >> 12;
  int n = idx & (N_DIM - 1);
  const float* p = x + (size_t)b * C_DIM * N_DIM + n;
  float s = 0.f;
#pragma unroll
  for (int c = 0; c < C_DIM; ++c) s += p[(size_t)c * N_DIM];
  E[idx] = __builtin_amdgcn_exp2f(s * (1.44269504f / C_DIM));
}

// Prep B: feabT tiled bf16: feabT[((b*128 + n/32)*32 + c)*32 + n%32]
__global__ __launch_bounds__(256) void prep_feab(const float* __restrict__ x,
                                                 ushort* __restrict__ feabT) {
  int idx = blockIdx.x * 256 + threadIdx.x;   // 0 .. 8*32*256-1
  int g = idx & 255;           // n-group of 16
  int c = (idx >> 8) & 31;
  int b = idx >> 13;
  int n0 = g * 16;
  const float* p = x + ((size_t)(b * C_DIM + c)) * N_DIM + n0;
  ushort* q = feabT + ((size_t)(b * (N_DIM / 32) + (n0 >> 5)) * C_DIM + c) * 32 + (n0 & 31);
  ushort8 v0, v1;
#pragma unroll
  for (int j = 0; j < 8; ++j) v0[j] = f2bf_rne(p[j]);
#pragma unroll
  for (int j = 0; j < 8; ++j) v1[j] = f2bf_rne(p[8 + j]);
  *(ushort8*)q = v0;
  *(ushort8*)(q + 8) = v1;
}

// Fused: identical to r17 except the staged chunk is 64 k (tile 64x16, each
// thread stages 2 elements) -> HALF the barriers (64 vs 128) and 2x the VALU
// run between rendezvous. Everything else unchanged: 16 waves = 2 kh-groups
// x 8 batches, depth-2 register staging, stride-33 abuf, min-identity weight
// gen, fused kh-reduce + para*relu epilogue.
__global__ __launch_bounds__(1024, 4) void gcn_fused(
    const ushort* __restrict__ feabT, const float* __restrict__ adj,
    const float* __restrict__ E, const float* __restrict__ para,
    float* __restrict__ out) {
  __shared__ float abuf[2][64 * 33 + 4];   // ~17 KB, row stride 33
  __shared__ float red[B_DIM][512];        // 16 KB reduce buffer

  const int tid = threadIdx.x;
  const int lane = tid & 63;
  const int w = tid >> 6;           // 0..15
  const int b = w & 7;              // batch
  const int kh = w >> 3;            // 0..1 = K-half
  const int quad = lane >> 4;
  const int l15 = lane & 15;
  const int colgrp = blockIdx.x;    // 0..255
  const int col = colgrp * 16 + l15;
  const int ksbase = kh * KSL;

  // staging: kh-group's 512 threads cover the 64x16 tile, 2 elems each
  const int tg = tid & 511;
  const int srow = tg >> 4;         // 0..31 (also covers srow+32)
  const int scol = tg & 15;
  const float* agp0 = adj + (size_t)(ksbase + srow) * N_DIM + colgrp * 16 + scol;
  const float* agp1 = agp0 + (size_t)32 * N_DIM;
  const int swaddr0 = srow * 33 + scol;
  const int swaddr1 = (srow + 32) * 33 + scol;

  const float* Eb = E + (size_t)b * N_DIM;
  const float Em = Eb[col];
  const float* ekb = Eb + ksbase;
  const ushort* fb = feabT + ((size_t)b * (N_DIM / 32) + (ksbase >> 5)) * (C_DIM * 32);

  f32x4 acc0 = {0.f, 0.f, 0.f, 0.f};   // channels 0-15
  f32x4 acc1 = {0.f, 0.f, 0.f, 0.f};   // channels 16-31

  // depth-2 staging pipeline, 2 values per thread per tile
  float anx0 = agp0[0], any0 = agp1[0];                        // tile ch+1 vals
  float anx2 = agp0[(size_t)64 * N_DIM], any2 = agp1[(size_t)64 * N_DIM];
  abuf[kh][swaddr0] = 2.0f * anx0;   // tile 0 into LDS
  abuf[kh][swaddr1] = 2.0f * any0;
  anx0 = anx2;
  any0 = any2;
  __syncthreads();

  for (int ch = 0; ch < NCH; ++ch) {
    // issue tile ch+2's staging loads now (~2 chunks of distance)
    if (ch + 2 < NCH) {
      anx2 = agp0[(size_t)(ch + 2) * 64 * N_DIM];
      any2 = agp1[(size_t)(ch + 2) * 64 * N_DIM];
    }

#pragma unroll
    for (int ksub = 0; ksub < 2; ++ksub) {
      const int c32 = ch * 2 + ksub;   // 32-k subchunk index
      const ushort* tile = fb + (size_t)c32 * (C_DIM * 32);
      const bf16x8 fa0 = *(const bf16x8*)(tile + l15 * 32 + quad * 8);
      const bf16x8 fa1 = *(const bf16x8*)(tile + (16 + l15) * 32 + quad * 8);
      float ekv[8];
      *(f32x4*)&ekv[0] = *(const f32x4*)(ekb + c32 * 32 + quad * 8);
      *(f32x4*)&ekv[4] = *(const f32x4*)(ekb + c32 * 32 + quad * 8 + 4);

      float a2[8];
#pragma unroll
      for (int j = 0; j < 8; ++j)
        a2[j] = abuf[kh][(ksub * 32 + quad * 8 + j) * 33 + l15];

      // w = (2*adj) * min(Ek,Em) * rcp(Ek+Em)   (exact identity)
      uint4v wfu;
#pragma unroll
      for (int p = 0; p < 4; ++p) {
        const float e0 = ekv[2 * p];
        const float e1 = ekv[2 * p + 1];
        const float t0 = fminf(e0, Em);
        const float t1 = fminf(e1, Em);
        const float s0 = e0 + Em;
        const float s1 = e1 + Em;
        const float w0 = a2[2 * p] * t0 * __builtin_amdgcn_rcpf(s0);
        const float w1 = a2[2 * p + 1] * t1 * __builtin_amdgcn_rcpf(s1);
        // truncating bf16x2 pack: bytes [w0.b2, w0.b3, w1.b2, w1.b3]
        wfu[p] = __builtin_amdgcn_perm(__float_as_uint(w1), __float_as_uint(w0),
                                       0x07060302u);
      }
      const bf16x8 wf = __builtin_bit_cast(bf16x8, wfu);

      acc0 = __builtin_amdgcn_mfma_f32_16x16x32_bf16(fa0, wf, acc0, 0, 0, 0);
      acc1 = __builtin_amdgcn_mfma_f32_16x16x32_bf16(fa1, wf, acc1, 0, 0, 0);
    }

    __syncthreads();   // all waves done reading their abuf tile for chunk ch
    if (ch + 1 < NCH) {
      abuf[kh][swaddr0] = 2.0f * anx0;   // values loaded >=1 full chunk ago
      abuf[kh][swaddr1] = 2.0f * any0;
      anx0 = anx2;
      any0 = any2;
    }
    __syncthreads();   // staged writes visible
  }

  // fused kh-reduce + epilogue (D layout: col=l15, row=quad*4+r)
  if (kh == 1) {
#pragma unroll
    for (int r = 0; r < 4; ++r) {
      red[b][(quad * 4 + r) * 16 + l15] = acc0[r];
      red[b][(16 + quad * 4 + r) * 16 + l15] = acc1[r];
    }
  }
  __syncthreads();
  if (kh == 0) {
#pragma unroll
    for (int r = 0; r < 4; ++r) {
      const int c0 = quad * 4 + r;
      const int c1 = c0 + 16;
      float s0 = acc0[r] + red[b][c0 * 16 + l15];
      float s1 = acc1[r] + red[b][c1 * 16 + l15];
      s0 *= para[(size_t)c0 * N_DIM + col];
      s1 *= para[(size_t)c1 * N_DIM + col];
      out[((size_t)(b * C_DIM + c0)) * N_DIM + col] = fmaxf(s0, 0.f);
      out[((size_t)(b * C_DIM + c1)) * N_DIM + col] = fmaxf(s1, 0.f);
    }
  }
}

extern "C" void kernel_launch(void* const* d_in, const int* in_sizes, int n_in,
                              void* d_out, int out_size, void* d_ws, size_t ws_size,
                              hipStream_t stream) {
  const float* x = (const float*)d_in[0];     // [8,32,64,64]
  const float* para = (const float*)d_in[1];  // [1,32,64,64]
  const float* adj = (const float*)d_in[2];   // [4096,4096]
  float* out = (float*)d_out;

  // ws: E (128 KB) | feabT (2 MB) -- total 2.25 MB
  float* E = (float*)d_ws;
  ushort* feabT = (ushort*)(E + (size_t)B_DIM * N_DIM);

  prep_e<<<dim3(B_DIM * N_DIM / 256), dim3(256), 0, stream>>>(x, E);
  prep_feab<<<dim3(B_DIM * C_DIM * (N_DIM / 16) / 256), dim3(256), 0, stream>>>(x, feabT);
  gcn_fused<<<dim3(N_DIM / 16), dim3(1024), 0, stream>>>(feabT, adj, E, para, out);
}